// Round 13
// baseline (77.666 us; speedup 1.0000x reference)
//
#include <hip/hip_runtime.h>
#include <hip/hip_bf16.h>
#include <math.h>

#define NN 768
#define DD 256
#define NHEAD 4
#define HDIM 64
#define TOPK 16

typedef __attribute__((ext_vector_type(8))) short short8;
typedef __attribute__((ext_vector_type(4))) float f32x4;

__device__ __forceinline__ unsigned short f2bf(float f) {
    unsigned u = __float_as_uint(f);
    unsigned r = u + 0x7fffu + ((u >> 16) & 1u);
    return (unsigned short)(r >> 16);
}

// ---- fused stage 1: weight transpose->bf16 (0..575) + norms/adj (576..767)
//                     + out_w elementwise bf16 copy (768..831)
__global__ __launch_bounds__(256) void k_prep_norms(
        const float* __restrict__ Wqkv,
        const float* __restrict__ outw,
        const float* __restrict__ f1w,  const float* __restrict__ f2w,
        unsigned short* __restrict__ t_qkv,
        unsigned short* __restrict__ t_f1,  unsigned short* __restrict__ t_f2,
        unsigned short* __restrict__ t_g,   unsigned short* __restrict__ t_outn,
        const float* __restrict__ x,
        double* __restrict__ nrm2_d, double* __restrict__ nrm_d,
        double* __restrict__ invn_d,
        unsigned short* __restrict__ xb, unsigned int* __restrict__ adjw) {
    int b = blockIdx.x;
    int tid = threadIdx.x;
    if (b < 576) {
        const float* src; unsigned short* dst; int K, C, tile;
        if (b < 192)      { src = Wqkv; dst = t_qkv; K = 256; C = 768; tile = b; }
        else if (b < 448) { src = f1w;  dst = t_f1;  K = 512; C = 512; tile = b - 192; }
        else              { src = f2w;  dst = t_f2;  K = 512; C = 256; tile = b - 448; }
        int tpr = C / 32;
        int k0 = (tile / tpr) * 32, c0 = (tile % tpr) * 32;
        __shared__ float tls[32][33];
        int r = tid >> 3, c4 = (tid & 7) * 4;
        float4 v = *(const float4*)&src[(size_t)(k0 + r) * C + c0 + c4];
        tls[r][c4 + 0] = v.x; tls[r][c4 + 1] = v.y;
        tls[r][c4 + 2] = v.z; tls[r][c4 + 3] = v.w;
        __syncthreads();
        int rc = tid >> 3, k4 = (tid & 7) * 4;
        unsigned short* d = &dst[(size_t)(c0 + rc) * K + k0 + k4];
        unsigned short w0 = f2bf(tls[k4 + 0][rc]);
        unsigned short w1 = f2bf(tls[k4 + 1][rc]);
        unsigned short w2 = f2bf(tls[k4 + 2][rc]);
        unsigned short w3 = f2bf(tls[k4 + 3][rc]);
        d[0] = w0; d[1] = w1; d[2] = w2; d[3] = w3;
        // mirror the TOP half of t_f1 into t_g (bottom half filled by Wf GEMM)
        if (b >= 192 && b < 448 && k0 < 256) {
            unsigned short* d2 = &t_g[(size_t)(c0 + rc) * 512 + k0 + k4];
            d2[0] = w0; d2[1] = w1; d2[2] = w2; d2[3] = w3;
        }
    } else if (b < 768) {
        int nb = b - 576;
        int gid = nb * 256 + tid;
        adjw[gid * 3 + 0] = 0u;
        adjw[gid * 3 + 1] = 0u;
        adjw[gid * 3 + 2] = 0u;
        int n = nb * 4 + (tid >> 6);
        int lane = tid & 63;
        const float* row = x + (size_t)n * DD;
        double s = 0.0;
        #pragma unroll
        for (int i = 0; i < 4; ++i) {
            float v = row[lane + 64 * i];
            xb[(size_t)n * DD + lane + 64 * i] = f2bf(v);
            s += (double)v * (double)v;
        }
        for (int off = 32; off > 0; off >>= 1) s += __shfl_down(s, off);
        if (lane == 0) {
            nrm2_d[n] = s;
            double nv = sqrt(s);
            nrm_d[n] = nv;
            invn_d[n] = 1.0 / fmax(nv, 1e-12);
        }
    } else {
        // elementwise bf16 copy of out_w (row-major, NOT transposed)
        int idx = (b - 768) * 1024 + tid * 4;
        float4 v = *(const float4*)&outw[idx];
        t_outn[idx + 0] = f2bf(v.x);
        t_outn[idx + 1] = f2bf(v.y);
        t_outn[idx + 2] = f2bf(v.z);
        t_outn[idx + 3] = f2bf(v.w);
    }
}

// ---- fused stage 2: fp64 similarity (0..299, fp64-LDS, split-K triangle)
//      + qkv MFMA GEMM (300..587) + Wf GEMM (588..651) + fused bias (652)
__global__ __launch_bounds__(512) void k_simqkv(
        const float* __restrict__ x, const double* __restrict__ invn_d,
        double* __restrict__ simd,
        const unsigned short* __restrict__ xbf,
        const unsigned short* __restrict__ t_qkv,
        const float* __restrict__ Wqkv_b,
        float* __restrict__ qb, float* __restrict__ kb, float* __restrict__ vb,
        const unsigned short* __restrict__ t_f1,
        const unsigned short* __restrict__ t_outn,
        unsigned short* __restrict__ t_g,
        const float* __restrict__ out_b, const float* __restrict__ f1w,
        const float* __restrict__ ffn1_b, float* __restrict__ bias_f) {
    __shared__ double Ad[2][32][38];
    __shared__ double Bd[2][32][38];
    int b = blockIdx.x;
    int tid = threadIdx.x;
    if (b < 300) {
        int r = (int)((sqrtf(8.f * (float)b + 1.f) - 1.f) * 0.5f);
        while ((r + 1) * (r + 2) / 2 <= b) ++r;
        while (r * (r + 1) / 2 > b) --r;
        int c = b - r * (r + 1) / 2;
        int n0 = c * 32, m0 = r * 32;   // m0 >= n0

        int g = tid >> 8;          // K-half group
        int t = tid & 255;
        int tx = t & 15, ty = t >> 4;
        int srow = t >> 3;             // staging row 0..31
        int skq  = (t & 7) * 4;        // staging k-quad
        double d00 = 0.0, d01 = 0.0, d10 = 0.0, d11 = 0.0;

        #pragma unroll
        for (int ch = 0; ch < 4; ++ch) {
            int d0 = g * 128 + ch * 32;
            float4 av = *(const float4*)&x[(size_t)(n0 + srow) * DD + d0 + skq];
            float4 bv = *(const float4*)&x[(size_t)(m0 + srow) * DD + d0 + skq];
            // convert ONCE on store (exact f32->f64)
            Ad[g][srow][skq + 0] = (double)av.x;
            Ad[g][srow][skq + 1] = (double)av.y;
            Ad[g][srow][skq + 2] = (double)av.z;
            Ad[g][srow][skq + 3] = (double)av.w;
            Bd[g][srow][skq + 0] = (double)bv.x;
            Bd[g][srow][skq + 1] = (double)bv.y;
            Bd[g][srow][skq + 2] = (double)bv.z;
            Bd[g][srow][skq + 3] = (double)bv.w;
            __syncthreads();
            #pragma unroll
            for (int d = 0; d < 32; d += 4) {
                double a0x = Ad[g][ty][d + 0], a0y = Ad[g][ty][d + 1];
                double a0z = Ad[g][ty][d + 2], a0w = Ad[g][ty][d + 3];
                double a1x = Ad[g][ty + 16][d + 0], a1y = Ad[g][ty + 16][d + 1];
                double a1z = Ad[g][ty + 16][d + 2], a1w = Ad[g][ty + 16][d + 3];
                double b0x = Bd[g][tx][d + 0], b0y = Bd[g][tx][d + 1];
                double b0z = Bd[g][tx][d + 2], b0w = Bd[g][tx][d + 3];
                double b1x = Bd[g][tx + 16][d + 0], b1y = Bd[g][tx + 16][d + 1];
                double b1z = Bd[g][tx + 16][d + 2], b1w = Bd[g][tx + 16][d + 3];
                d00 += a0x * b0x + a0y * b0y + a0z * b0z + a0w * b0w;
                d01 += a0x * b1x + a0y * b1y + a0z * b1z + a0w * b1w;
                d10 += a1x * b0x + a1y * b0y + a1z * b0z + a1w * b0w;
                d11 += a1x * b1x + a1y * b1y + a1z * b1z + a1w * b1w;
            }
            __syncthreads();
        }

        double* part = &Ad[0][0][0];
        if (g == 1) {
            part[t * 4 + 0] = d00; part[t * 4 + 1] = d01;
            part[t * 4 + 2] = d10; part[t * 4 + 3] = d11;
        }
        __syncthreads();
        if (g == 0) {
            d00 += part[t * 4 + 0]; d01 += part[t * 4 + 1];
            d10 += part[t * 4 + 2]; d11 += part[t * 4 + 3];
            double in_m0 = invn_d[m0 + tx], in_m1 = invn_d[m0 + tx + 16];
            double in_n0 = invn_d[n0 + ty], in_n1 = invn_d[n0 + ty + 16];
            double v00 = d00 * in_n0 * in_m0;
            double v01 = d01 * in_n0 * in_m1;
            double v10 = d10 * in_n1 * in_m0;
            double v11 = d11 * in_n1 * in_m1;
            simd[(size_t)(n0 + ty) * NN + m0 + tx]           = v00;
            simd[(size_t)(n0 + ty) * NN + m0 + tx + 16]      = v01;
            simd[(size_t)(n0 + ty + 16) * NN + m0 + tx]      = v10;
            simd[(size_t)(n0 + ty + 16) * NN + m0 + tx + 16] = v11;
            simd[(size_t)(m0 + tx) * NN + n0 + ty]           = v00;
            simd[(size_t)(m0 + tx + 16) * NN + n0 + ty]      = v01;
            simd[(size_t)(m0 + tx) * NN + n0 + ty + 16]      = v10;
            simd[(size_t)(m0 + tx + 16) * NN + n0 + ty + 16] = v11;
        }
    } else if (b < 588) {
        int w = tid >> 6, lane = tid & 63;
        int id = (b - 300) * 8 + w;           // 0..2303 wave-tiles
        int rt = id % 48, ct = id / 48;
        int m0 = rt * 16, n0 = ct * 16;
        int fr = lane & 15, fg = lane >> 4;
        f32x4 acc = {0.f, 0.f, 0.f, 0.f};
        const unsigned short* brow = &t_qkv[(size_t)(n0 + fr) * DD];
        #pragma unroll
        for (int k0 = 0; k0 < DD; k0 += 32) {
            short8 a = *(const short8*)&xbf[(size_t)(m0 + fr) * DD + k0 + fg * 8];
            short8 bb8 = *(const short8*)&brow[k0 + fg * 8];
            acc = __builtin_amdgcn_mfma_f32_16x16x32_bf16(a, bb8, acc, 0, 0, 0);
        }
        int cidx = n0 + fr;
        int hh = cidx / 192, rem = cidx % 192, hd = rem / 3, s = rem % 3;
        float* dst = (s == 0) ? qb : (s == 1) ? kb : vb;
        float bb = Wqkv_b[cidx];
        #pragma unroll
        for (int r = 0; r < 4; ++r) {
            int n = m0 + fg * 4 + r;
            dst[((size_t)hh * NN + n) * HDIM + hd] = acc[r] + bb;
        }
    } else if (b < 652) {
        // Wf[j][c2] -> t_g[c2][256+j] bf16
        int w = tid >> 6, lane = tid & 63;
        int id = (b - 588) * 8 + w;           // 0..511 wave-tiles
        int m0 = (id & 31) * 16;              // c2
        int n0 = (id >> 5) * 16;              // j
        int fr = lane & 15, fg = lane >> 4;
        f32x4 acc = {0.f, 0.f, 0.f, 0.f};
        const unsigned short* arow = &t_f1[(size_t)(m0 + fr) * 512 + 256];
        const unsigned short* brow = &t_outn[(size_t)(n0 + fr) * 256];
        #pragma unroll
        for (int k0 = 0; k0 < 256; k0 += 32) {
            short8 a = *(const short8*)&arow[k0 + fg * 8];
            short8 bb8 = *(const short8*)&brow[k0 + fg * 8];
            acc = __builtin_amdgcn_mfma_f32_16x16x32_bf16(a, bb8, acc, 0, 0, 0);
        }
        #pragma unroll
        for (int r = 0; r < 4; ++r)
            t_g[(size_t)(m0 + fg * 4 + r) * 512 + 256 + n0 + fr] = f2bf(acc[r]);
    } else {
        // fused ffn1 bias
        float s = ffn1_b[tid];
        for (int c = 0; c < 256; ++c)
            s += out_b[c] * f1w[(size_t)(256 + c) * 512 + tid];
        bias_f[tid] = s;
    }
}

// ---------------- top-k (K=16): one wave per row, zero barriers
__global__ __launch_bounds__(256) void k_topk(const double* __restrict__ simd,
                                              unsigned char* __restrict__ adj) {
    int tid = threadIdx.x;
    int w = tid >> 6, l = tid & 63;
    int n = blockIdx.x * 4 + w;
    const double* row = simd + (size_t)n * NN;
    double v[12];
    #pragma unroll
    for (int i = 0; i < 12; ++i) {
        int m = l + 64 * i;
        v[i] = (m == n) ? -INFINITY : row[m];
    }
    if (l == 0) adj[(size_t)n * NN + n] = 1;

    for (int itr = 0; itr < TOPK; ++itr) {
        double bv = -INFINITY; int bi = 0x7fffffff;
        #pragma unroll
        for (int i = 0; i < 12; ++i) {
            if (v[i] > bv) { bv = v[i]; bi = l + 64 * i; }
        }
        #pragma unroll
        for (int off = 32; off > 0; off >>= 1) {
            double ov = __shfl_down(bv, off);
            int    oi = __shfl_down(bi, off);
            if (ov > bv || (ov == bv && oi < bi)) { bv = ov; bi = oi; }
        }
        bi = __shfl(bi, 0);
        if ((bi & 63) == l) {
            int slot = bi >> 6;
            #pragma unroll
            for (int i = 0; i < 12; ++i) if (i == slot) v[i] = -INFINITY;
        }
        if (l == 0) {
            adj[(size_t)n * NN + bi] = 1;
            adj[(size_t)bi * NN + n] = 1;
        }
    }
}

// ---- fused: nbr-list build + edge features + edge MLP + sparse attention
__global__ __launch_bounds__(256) void k_edge_attn(
        const float* __restrict__ x,
        const double* __restrict__ nrm2_d,
        const double* __restrict__ nrm_d,
        const double* __restrict__ simd,
        const unsigned char* __restrict__ adj,
        const float* __restrict__ e1_w, const float* __restrict__ e1_b,
        const float* __restrict__ e2_w, const float* __restrict__ e2_b,
        const float* __restrict__ gate_p,
        const float* __restrict__ q, const float* __restrict__ k,
        const float* __restrict__ v,
        unsigned short* __restrict__ ctxb) {
    int n = blockIdx.x;
    int tid = threadIdx.x;
    int w = tid >> 6, l = tid & 63;
    __shared__ unsigned short idxs[NN];
    __shared__ float w_sh[NHEAD][NN];
    __shared__ float ef2s[NN];
    __shared__ float ef3s[NN];
    __shared__ float qsh[NHEAD][HDIM];
    __shared__ int wtot[4];

    int c = 0; int loc[3];
    #pragma unroll
    for (int i = 0; i < 3; ++i) {
        int m = 3 * tid + i;
        if (adj[(size_t)n * NN + m]) loc[c++] = m;
    }
    int pc = c;
    #pragma unroll
    for (int off = 1; off < 64; off <<= 1) {
        int o = __shfl_up(pc, off);
        if (l >= off) pc += o;
    }
    if (l == 63) wtot[w] = pc;
    qsh[w][l] = q[((size_t)w * NN + n) * HDIM + l];
    __syncthreads();
    int base = 0;
    #pragma unroll
    for (int ww = 0; ww < 4; ++ww) if (ww < w) base += wtot[ww];
    int start = base + pc - c;
    for (int i = 0; i < c; ++i) idxs[start + i] = (unsigned short)loc[i];
    int cnt = wtot[0] + wtot[1] + wtot[2] + wtot[3];
    __syncthreads();

    float xa[4];
    #pragma unroll
    for (int i = 0; i < 4; ++i) xa[i] = x[(size_t)n * DD + l + 64 * i];

    for (int j = w; j < cnt; j += 4) {
        int m = idxs[j];
        float sab = 0.f, mab = 0.f;
        #pragma unroll
        for (int i = 0; i < 4; ++i) {
            float xb = x[(size_t)m * DD + l + 64 * i];
            float ad = fabsf(xa[i] - xb);
            sab += ad;
            mab = fmaxf(mab, ad);
        }
        #pragma unroll
        for (int off = 32; off > 0; off >>= 1) {
            sab += __shfl_xor(sab, off);
            mab = fmaxf(mab, __shfl_xor(mab, off));
        }
        if (l == 0) { ef2s[j] = sab * (1.f / 256.f); ef3s[j] = mab; }
    }
    __syncthreads();

    double nrm2n = nrm2_d[n];
    double nrmn  = nrm_d[n];
    float gate = gate_p[0];
    for (int j0 = 0; j0 < cnt; j0 += 64) {
        int j = j0 + (tid >> 2);
        int hh = tid & 3;
        if (j < cnt) {
            int m = idxs[j];
            double s_d   = simd[(size_t)n * NN + m];
            double nrm2m = nrm2_d[m];
            double dotd  = s_d * nrmn * nrm_d[m];
            double l2sq  = fmax(nrm2n + nrm2m - 2.0 * dotd, 0.0);
            float ef0 = (float)s_d;
            float ef1 = (float)(sqrt(l2sq) * (1.0 / 16.0));
            float ef2 = ef2s[j];
            float ef3 = ef3s[j];
            float bb = e2_b[hh];
            #pragma unroll
            for (int jj = 0; jj < 8; ++jj) {
                float hv = e1_b[jj] + ef0 * e1_w[0 * 8 + jj] + ef1 * e1_w[1 * 8 + jj]
                         + ef2 * e1_w[2 * 8 + jj] + ef3 * e1_w[3 * 8 + jj];
                bb += fmaxf(hv, 0.f) * e2_w[jj * 4 + hh];
            }
            w_sh[hh][j] = gate * bb;
        }
    }
    __syncthreads();

    int h = w;
    float lmax = -INFINITY;
    for (int j = l; j < cnt; j += 64) {
        int m = idxs[j];
        const float4* kr = (const float4*)(k + ((size_t)h * NN + m) * HDIM);
        float dotv = 0.f;
        #pragma unroll
        for (int d4 = 0; d4 < HDIM / 4; ++d4) {
            float4 kv = kr[d4];
            dotv += qsh[h][4 * d4 + 0] * kv.x + qsh[h][4 * d4 + 1] * kv.y
                  + qsh[h][4 * d4 + 2] * kv.z + qsh[h][4 * d4 + 3] * kv.w;
        }
        w_sh[h][j] = dotv * 0.125f + w_sh[h][j];
        lmax = fmaxf(lmax, w_sh[h][j]);
    }
    #pragma unroll
    for (int off = 32; off > 0; off >>= 1)
        lmax = fmaxf(lmax, __shfl_xor(lmax, off));

    float lsum = 0.f;
    for (int j = l; j < cnt; j += 64) {
        float e = expf(w_sh[h][j] - lmax);
        w_sh[h][j] = e;
        lsum += e;
    }
    #pragma unroll
    for (int off = 32; off > 0; off >>= 1) lsum += __shfl_xor(lsum, off);
    float inv = 1.f / lsum;
    __syncthreads();

    float acc = 0.f;
    #pragma unroll 4
    for (int j = 0; j < cnt; ++j)
        acc += w_sh[h][j] * v[((size_t)h * NN + idxs[j]) * HDIM + l];
    ctxb[(size_t)n * DD + h * HDIM + l] = f2bf(acc * inv);
}

// -------- LDS-free register MFMA GEMM (ffn1): wave owns one 16x16 tile
template<int KD, int MODE, bool CONCAT>
__global__ __launch_bounds__(256) void k_gemm_reg(const unsigned short* __restrict__ A,
                                                  const unsigned short* __restrict__ A2,
                                                  const unsigned short* __restrict__ Bt,
                                                  const float* __restrict__ bias,
                                                  const float* __restrict__ resid,
                                                  float* __restrict__ out,
                                                  unsigned short* __restrict__ outb,
                                                  int ncols) {
    int tid = threadIdx.x;
    int w = tid >> 6, lane = tid & 63;
    int m0 = blockIdx.y * 64 + w * 16;
    int n0 = blockIdx.x * 16;
    int fr = lane & 15, fg = lane >> 4;
    f32x4 acc = {0.f, 0.f, 0.f, 0.f};

    const unsigned short* brow = &Bt[(size_t)(n0 + fr) * KD];
    #pragma unroll
    for (int k0 = 0; k0 < KD; k0 += 32) {
        const unsigned short* Asrc = A; int koff = k0;
        if (CONCAT && k0 >= 256) { Asrc = A2; koff = k0 - 256; }
        int lda = CONCAT ? 256 : KD;
        short8 a = *(const short8*)&Asrc[(size_t)(m0 + fr) * lda + koff + fg * 8];
        short8 b = *(const short8*)&brow[k0 + fg * 8];
        acc = __builtin_amdgcn_mfma_f32_16x16x32_bf16(a, b, acc, 0, 0, 0);
    }

    int cidx = n0 + fr;
    float bb = bias[cidx];
    #pragma unroll
    for (int r = 0; r < 4; ++r) {
        int n = m0 + fg * 4 + r;
        float val = acc[r] + bb;
        if (MODE == 1) val += resid[(size_t)n * ncols + cidx];
        if (MODE == 3) outb[(size_t)n * ncols + cidx] = f2bf(val);
        else           out [(size_t)n * ncols + cidx] = val;
    }
}

// ---- fused LN + exact GELU + ffn2 GEMM + residual
// grid (4, 48): bx = 64-col group, by = 16-row group; 256 thr (4 waves)
__global__ __launch_bounds__(256) void k_ffn2_ln(
        const float* __restrict__ yb,
        const float* __restrict__ ln_g, const float* __restrict__ ln_b,
        const unsigned short* __restrict__ t_f2,
        const float* __restrict__ ffn2_b,
        const float* __restrict__ x, float* __restrict__ outp) {
    __shared__ unsigned short ysm[16][520];   // +8 bf16 pad: 2-way banks
    int tid = threadIdx.x;
    int w = tid >> 6, lane = tid & 63;
    int m0 = blockIdx.y * 16;
    int c0 = blockIdx.x * 64 + w * 16;
    int fr = lane & 15, fg = lane >> 4;

    // LN + GELU: wave w handles local rows w*4 .. w*4+3
    #pragma unroll
    for (int rr = 0; rr < 4; ++rr) {
        int row = w * 4 + rr;
        const float* yrow = yb + (size_t)(m0 + row) * 512;
        float vv[8];
        float s = 0.f;
        #pragma unroll
        for (int i = 0; i < 8; ++i) { vv[i] = yrow[lane + 64 * i]; s += vv[i]; }
        #pragma unroll
        for (int off = 32; off > 0; off >>= 1) s += __shfl_xor(s, off);
        float mu = s * (1.f / 512.f);
        float qs = 0.f;
        #pragma unroll
        for (int i = 0; i < 8; ++i) { float d = vv[i] - mu; qs += d * d; }
        #pragma unroll
        for (int off = 32; off > 0; off >>= 1) qs += __shfl_xor(qs, off);
        float rstd = 1.f / sqrtf(qs * (1.f / 512.f) + 1e-5f);
        #pragma unroll
        for (int i = 0; i < 8; ++i) {
            int cidx = lane + 64 * i;
            float z = (vv[i] - mu) * rstd * ln_g[cidx] + ln_b[cidx];
            float o = 0.5f * z * (1.f + erff(z * 0.70710678118654752f));
            ysm[row][cidx] = f2bf(o);
        }
    }
    __syncthreads();

    // MFMA: A = ysm rows 0..15 (local), B = t_f2 cols c0..c0+15
    f32x4 acc = {0.f, 0.f, 0.f, 0.f};
    const unsigned short* brow = &t_f2[(size_t)(c0 + fr) * 512];
    #pragma unroll
    for (int k0 = 0; k0 < 512; k0 += 32) {
        short8 a = *(const short8*)&ysm[fr][k0 + fg * 8];
        short8 b = *(const short8*)&brow[k0 + fg * 8];
        acc = __builtin_amdgcn_mfma_f32_16x16x32_bf16(a, b, acc, 0, 0, 0);
    }
    int cidx = c0 + fr;
    float bb = ffn2_b[cidx];
    #pragma unroll
    for (int r = 0; r < 4; ++r) {
        int n = m0 + fg * 4 + r;
        outp[(size_t)n * DD + cidx] = acc[r] + bb + x[(size_t)n * DD + cidx];
    }
}

// --------------------------------------------------------------------- host
extern "C" void kernel_launch(void* const* d_in, const int* in_sizes, int n_in,
                              void* d_out, int out_size, void* d_ws, size_t ws_size,
                              hipStream_t stream) {
    const float* x       = (const float*)d_in[0];
    const float* Wqkv_w  = (const float*)d_in[1];
    const float* Wqkv_b  = (const float*)d_in[2];
    const float* out_w   = (const float*)d_in[3];
    const float* out_b   = (const float*)d_in[4];
    const float* ffn1_w  = (const float*)d_in[5];
    const float* ffn1_b  = (const float*)d_in[6];
    const float* ln_g    = (const float*)d_in[7];
    const float* ln_b    = (const float*)d_in[8];
    const float* ffn2_w  = (const float*)d_in[9];
    const float* ffn2_b  = (const float*)d_in[10];
    const float* e1_w    = (const float*)d_in[11];
    const float* e1_b    = (const float*)d_in[12];
    const float* e2_w    = (const float*)d_in[13];
    const float* e2_b    = (const float*)d_in[14];
    const float* gate    = (const float*)d_in[15];

    char* base = (char*)d_ws;
    double* simd   = (double*)base;            base += (size_t)NN * NN * 8;
    double* nrm2_d = (double*)base;            base += NN * 8;
    double* nrm_d  = (double*)base;            base += NN * 8;
    double* invn_d = (double*)base;            base += NN * 8;
    float* qb      = (float*)base;             base += (size_t)NN * DD * 4;
    float* kb      = (float*)base;             base += (size_t)NN * DD * 4;
    float* vb      = (float*)base;             base += (size_t)NN * DD * 4;
    float* yb      = (float*)base;             base += (size_t)NN * 512 * 4;
    unsigned char* adj = (unsigned char*)base;  base += (size_t)NN * NN;
    unsigned short* xbf  = (unsigned short*)base; base += (size_t)NN * DD * 2;
    unsigned short* ctxb = (unsigned short*)base; base += (size_t)NN * DD * 2;
    unsigned short* t_qkv = (unsigned short*)base; base += (size_t)768 * 256 * 2;
    unsigned short* t_f1  = (unsigned short*)base; base += (size_t)512 * 512 * 2;
    unsigned short* t_f2  = (unsigned short*)base; base += (size_t)256 * 512 * 2;
    unsigned short* t_g   = (unsigned short*)base; base += (size_t)512 * 512 * 2;
    unsigned short* t_outn = (unsigned short*)base; base += (size_t)256 * 256 * 2;
    float* bias_f  = (float*)base;             base += 512 * 4;

    k_prep_norms<<<832, 256, 0, stream>>>(Wqkv_w, out_w, ffn1_w, ffn2_w,
                                          t_qkv, t_f1, t_f2, t_g, t_outn,
                                          x, nrm2_d, nrm_d, invn_d, xbf,
                                          (unsigned int*)adj);

    k_simqkv<<<653, 512, 0, stream>>>(x, invn_d, simd, xbf, t_qkv, Wqkv_b,
                                      qb, kb, vb, t_f1, t_outn, t_g,
                                      out_b, ffn1_w, ffn1_b, bias_f);

    k_topk<<<192, 256, 0, stream>>>(simd, adj);

    k_edge_attn<<<NN, 256, 0, stream>>>(x, nrm2_d, nrm_d, simd, adj,
                                        e1_w, e1_b, e2_w, e2_b, gate,
                                        qb, kb, vb, ctxb);

    // y = x @ W1_top + ctx @ Wf + bias_f   (fp32 out)
    k_gemm_reg<512, 0, true><<<dim3(32, 12), 256, 0, stream>>>(
        xbf, ctxb, t_g, bias_f, nullptr, yb, nullptr, 512);

    // out = x + GELU(LN(y)) @ ffn2_w + ffn2_b   (fused)
    k_ffn2_ln<<<dim3(4, 48), 256, 0, stream>>>(
        yb, ln_g, ln_b, t_f2, ffn2_b, x, (float*)d_out);
}

// Round 14
// 72.240 us; speedup vs baseline: 1.0751x; 1.0751x over previous
//
#include <hip/hip_runtime.h>
#include <hip/hip_bf16.h>
#include <math.h>

#define NN 768
#define DD 256
#define NHEAD 4
#define HDIM 64
#define TOPK 16

typedef __attribute__((ext_vector_type(8))) short short8;
typedef __attribute__((ext_vector_type(4))) float f32x4;

__device__ __forceinline__ unsigned short f2bf(float f) {
    unsigned u = __float_as_uint(f);
    unsigned r = u + 0x7fffu + ((u >> 16) & 1u);
    return (unsigned short)(r >> 16);
}

// ---- fused stage 1: weight transpose->bf16 (0..575) + norms/adj (576..767)
//                     + out_w elementwise bf16 copy (768..831)
__global__ __launch_bounds__(256) void k_prep_norms(
        const float* __restrict__ Wqkv,
        const float* __restrict__ outw,
        const float* __restrict__ f1w,  const float* __restrict__ f2w,
        unsigned short* __restrict__ t_qkv,
        unsigned short* __restrict__ t_f1,  unsigned short* __restrict__ t_f2,
        unsigned short* __restrict__ t_g,   unsigned short* __restrict__ t_outn,
        const float* __restrict__ x,
        double* __restrict__ nrm2_d, double* __restrict__ nrm_d,
        double* __restrict__ invn_d,
        unsigned short* __restrict__ xb, unsigned int* __restrict__ adjw) {
    int b = blockIdx.x;
    int tid = threadIdx.x;
    if (b < 576) {
        const float* src; unsigned short* dst; int K, C, tile;
        if (b < 192)      { src = Wqkv; dst = t_qkv; K = 256; C = 768; tile = b; }
        else if (b < 448) { src = f1w;  dst = t_f1;  K = 512; C = 512; tile = b - 192; }
        else              { src = f2w;  dst = t_f2;  K = 512; C = 256; tile = b - 448; }
        int tpr = C / 32;
        int k0 = (tile / tpr) * 32, c0 = (tile % tpr) * 32;
        __shared__ float tls[32][33];
        int r = tid >> 3, c4 = (tid & 7) * 4;
        float4 v = *(const float4*)&src[(size_t)(k0 + r) * C + c0 + c4];
        tls[r][c4 + 0] = v.x; tls[r][c4 + 1] = v.y;
        tls[r][c4 + 2] = v.z; tls[r][c4 + 3] = v.w;
        __syncthreads();
        int rc = tid >> 3, k4 = (tid & 7) * 4;
        unsigned short* d = &dst[(size_t)(c0 + rc) * K + k0 + k4];
        unsigned short w0 = f2bf(tls[k4 + 0][rc]);
        unsigned short w1 = f2bf(tls[k4 + 1][rc]);
        unsigned short w2 = f2bf(tls[k4 + 2][rc]);
        unsigned short w3 = f2bf(tls[k4 + 3][rc]);
        d[0] = w0; d[1] = w1; d[2] = w2; d[3] = w3;
        // mirror the TOP half of t_f1 into t_g (bottom half filled by Wf GEMM)
        if (b >= 192 && b < 448 && k0 < 256) {
            unsigned short* d2 = &t_g[(size_t)(c0 + rc) * 512 + k0 + k4];
            d2[0] = w0; d2[1] = w1; d2[2] = w2; d2[3] = w3;
        }
    } else if (b < 768) {
        int nb = b - 576;
        int gid = nb * 256 + tid;
        adjw[gid * 3 + 0] = 0u;
        adjw[gid * 3 + 1] = 0u;
        adjw[gid * 3 + 2] = 0u;
        int n = nb * 4 + (tid >> 6);
        int lane = tid & 63;
        const float* row = x + (size_t)n * DD;
        double s = 0.0;
        #pragma unroll
        for (int i = 0; i < 4; ++i) {
            float v = row[lane + 64 * i];
            xb[(size_t)n * DD + lane + 64 * i] = f2bf(v);
            s += (double)v * (double)v;
        }
        for (int off = 32; off > 0; off >>= 1) s += __shfl_down(s, off);
        if (lane == 0) {
            nrm2_d[n] = s;
            double nv = sqrt(s);
            nrm_d[n] = nv;
            invn_d[n] = 1.0 / fmax(nv, 1e-12);
        }
    } else {
        // elementwise bf16 copy of out_w (row-major, NOT transposed)
        int idx = (b - 768) * 1024 + tid * 4;
        float4 v = *(const float4*)&outw[idx];
        t_outn[idx + 0] = f2bf(v.x);
        t_outn[idx + 1] = f2bf(v.y);
        t_outn[idx + 2] = f2bf(v.z);
        t_outn[idx + 3] = f2bf(v.w);
    }
}

// ---- fused stage 2: fp64 similarity (0..299, fp64-LDS, split-K triangle)
//      + qkv MFMA GEMM (300..587) + Wf GEMM (588..651) + fused bias (652)
__global__ __launch_bounds__(512) void k_simqkv(
        const float* __restrict__ x, const double* __restrict__ invn_d,
        double* __restrict__ simd,
        const unsigned short* __restrict__ xbf,
        const unsigned short* __restrict__ t_qkv,
        const float* __restrict__ Wqkv_b,
        float* __restrict__ qb, float* __restrict__ kb, float* __restrict__ vb,
        const unsigned short* __restrict__ t_f1,
        const unsigned short* __restrict__ t_outn,
        unsigned short* __restrict__ t_g,
        const float* __restrict__ out_b, const float* __restrict__ f1w,
        const float* __restrict__ ffn1_b, float* __restrict__ bias_f) {
    __shared__ double Ad[2][32][38];
    __shared__ double Bd[2][32][38];
    int b = blockIdx.x;
    int tid = threadIdx.x;
    if (b < 300) {
        int r = (int)((sqrtf(8.f * (float)b + 1.f) - 1.f) * 0.5f);
        while ((r + 1) * (r + 2) / 2 <= b) ++r;
        while (r * (r + 1) / 2 > b) --r;
        int c = b - r * (r + 1) / 2;
        int n0 = c * 32, m0 = r * 32;   // m0 >= n0

        int g = tid >> 8;          // K-half group
        int t = tid & 255;
        int tx = t & 15, ty = t >> 4;
        int srow = t >> 3;             // staging row 0..31
        int skq  = (t & 7) * 4;        // staging k-quad
        double d00 = 0.0, d01 = 0.0, d10 = 0.0, d11 = 0.0;

        #pragma unroll
        for (int ch = 0; ch < 4; ++ch) {
            int d0 = g * 128 + ch * 32;
            float4 av = *(const float4*)&x[(size_t)(n0 + srow) * DD + d0 + skq];
            float4 bv = *(const float4*)&x[(size_t)(m0 + srow) * DD + d0 + skq];
            Ad[g][srow][skq + 0] = (double)av.x;
            Ad[g][srow][skq + 1] = (double)av.y;
            Ad[g][srow][skq + 2] = (double)av.z;
            Ad[g][srow][skq + 3] = (double)av.w;
            Bd[g][srow][skq + 0] = (double)bv.x;
            Bd[g][srow][skq + 1] = (double)bv.y;
            Bd[g][srow][skq + 2] = (double)bv.z;
            Bd[g][srow][skq + 3] = (double)bv.w;
            __syncthreads();
            #pragma unroll
            for (int d = 0; d < 32; d += 4) {
                double a0x = Ad[g][ty][d + 0], a0y = Ad[g][ty][d + 1];
                double a0z = Ad[g][ty][d + 2], a0w = Ad[g][ty][d + 3];
                double a1x = Ad[g][ty + 16][d + 0], a1y = Ad[g][ty + 16][d + 1];
                double a1z = Ad[g][ty + 16][d + 2], a1w = Ad[g][ty + 16][d + 3];
                double b0x = Bd[g][tx][d + 0], b0y = Bd[g][tx][d + 1];
                double b0z = Bd[g][tx][d + 2], b0w = Bd[g][tx][d + 3];
                double b1x = Bd[g][tx + 16][d + 0], b1y = Bd[g][tx + 16][d + 1];
                double b1z = Bd[g][tx + 16][d + 2], b1w = Bd[g][tx + 16][d + 3];
                d00 += a0x * b0x + a0y * b0y + a0z * b0z + a0w * b0w;
                d01 += a0x * b1x + a0y * b1y + a0z * b1z + a0w * b1w;
                d10 += a1x * b0x + a1y * b0y + a1z * b0z + a1w * b0w;
                d11 += a1x * b1x + a1y * b1y + a1z * b1z + a1w * b1w;
            }
            __syncthreads();
        }

        double* part = &Ad[0][0][0];
        if (g == 1) {
            part[t * 4 + 0] = d00; part[t * 4 + 1] = d01;
            part[t * 4 + 2] = d10; part[t * 4 + 3] = d11;
        }
        __syncthreads();
        if (g == 0) {
            d00 += part[t * 4 + 0]; d01 += part[t * 4 + 1];
            d10 += part[t * 4 + 2]; d11 += part[t * 4 + 3];
            double in_m0 = invn_d[m0 + tx], in_m1 = invn_d[m0 + tx + 16];
            double in_n0 = invn_d[n0 + ty], in_n1 = invn_d[n0 + ty + 16];
            double v00 = d00 * in_n0 * in_m0;
            double v01 = d01 * in_n0 * in_m1;
            double v10 = d10 * in_n1 * in_m0;
            double v11 = d11 * in_n1 * in_m1;
            simd[(size_t)(n0 + ty) * NN + m0 + tx]           = v00;
            simd[(size_t)(n0 + ty) * NN + m0 + tx + 16]      = v01;
            simd[(size_t)(n0 + ty + 16) * NN + m0 + tx]      = v10;
            simd[(size_t)(n0 + ty + 16) * NN + m0 + tx + 16] = v11;
            simd[(size_t)(m0 + tx) * NN + n0 + ty]           = v00;
            simd[(size_t)(m0 + tx + 16) * NN + n0 + ty]      = v01;
            simd[(size_t)(m0 + tx) * NN + n0 + ty + 16]      = v10;
            simd[(size_t)(m0 + tx + 16) * NN + n0 + ty + 16] = v11;
        }
    } else if (b < 588) {
        int w = tid >> 6, lane = tid & 63;
        int id = (b - 300) * 8 + w;           // 0..2303 wave-tiles
        int rt = id % 48, ct = id / 48;
        int m0 = rt * 16, n0 = ct * 16;
        int fr = lane & 15, fg = lane >> 4;
        f32x4 acc = {0.f, 0.f, 0.f, 0.f};
        const unsigned short* brow = &t_qkv[(size_t)(n0 + fr) * DD];
        #pragma unroll
        for (int k0 = 0; k0 < DD; k0 += 32) {
            short8 a = *(const short8*)&xbf[(size_t)(m0 + fr) * DD + k0 + fg * 8];
            short8 bb8 = *(const short8*)&brow[k0 + fg * 8];
            acc = __builtin_amdgcn_mfma_f32_16x16x32_bf16(a, bb8, acc, 0, 0, 0);
        }
        int cidx = n0 + fr;
        int hh = cidx / 192, rem = cidx % 192, hd = rem / 3, s = rem % 3;
        float* dst = (s == 0) ? qb : (s == 1) ? kb : vb;
        float bb = Wqkv_b[cidx];
        #pragma unroll
        for (int r = 0; r < 4; ++r) {
            int n = m0 + fg * 4 + r;
            dst[((size_t)hh * NN + n) * HDIM + hd] = acc[r] + bb;
        }
    } else if (b < 652) {
        // Wf[j][c2] -> t_g[c2][256+j] bf16
        int w = tid >> 6, lane = tid & 63;
        int id = (b - 588) * 8 + w;           // 0..511 wave-tiles
        int m0 = (id & 31) * 16;              // c2
        int n0 = (id >> 5) * 16;              // j
        int fr = lane & 15, fg = lane >> 4;
        f32x4 acc = {0.f, 0.f, 0.f, 0.f};
        const unsigned short* arow = &t_f1[(size_t)(m0 + fr) * 512 + 256];
        const unsigned short* brow = &t_outn[(size_t)(n0 + fr) * 256];
        #pragma unroll
        for (int k0 = 0; k0 < 256; k0 += 32) {
            short8 a = *(const short8*)&arow[k0 + fg * 8];
            short8 bb8 = *(const short8*)&brow[k0 + fg * 8];
            acc = __builtin_amdgcn_mfma_f32_16x16x32_bf16(a, bb8, acc, 0, 0, 0);
        }
        #pragma unroll
        for (int r = 0; r < 4; ++r)
            t_g[(size_t)(m0 + fg * 4 + r) * 512 + 256 + n0 + fr] = f2bf(acc[r]);
    } else {
        // fused ffn1 bias
        float s = ffn1_b[tid];
        for (int c = 0; c < 256; ++c)
            s += out_b[c] * f1w[(size_t)(256 + c) * 512 + tid];
        bias_f[tid] = s;
    }
}

// ---------------- top-k (K=16): one wave per row, zero barriers
__global__ __launch_bounds__(256) void k_topk(const double* __restrict__ simd,
                                              unsigned char* __restrict__ adj) {
    int tid = threadIdx.x;
    int w = tid >> 6, l = tid & 63;
    int n = blockIdx.x * 4 + w;
    const double* row = simd + (size_t)n * NN;
    double v[12];
    #pragma unroll
    for (int i = 0; i < 12; ++i) {
        int m = l + 64 * i;
        v[i] = (m == n) ? -INFINITY : row[m];
    }
    if (l == 0) adj[(size_t)n * NN + n] = 1;

    for (int itr = 0; itr < TOPK; ++itr) {
        double bv = -INFINITY; int bi = 0x7fffffff;
        #pragma unroll
        for (int i = 0; i < 12; ++i) {
            if (v[i] > bv) { bv = v[i]; bi = l + 64 * i; }
        }
        #pragma unroll
        for (int off = 32; off > 0; off >>= 1) {
            double ov = __shfl_down(bv, off);
            int    oi = __shfl_down(bi, off);
            if (ov > bv || (ov == bv && oi < bi)) { bv = ov; bi = oi; }
        }
        bi = __shfl(bi, 0);
        if ((bi & 63) == l) {
            int slot = bi >> 6;
            #pragma unroll
            for (int i = 0; i < 12; ++i) if (i == slot) v[i] = -INFINITY;
        }
        if (l == 0) {
            adj[(size_t)n * NN + bi] = 1;
            adj[(size_t)bi * NN + n] = 1;
        }
    }
}

// ---- fused: nbr-list build + edge features + edge MLP + sparse attention
__global__ __launch_bounds__(256) void k_edge_attn(
        const float* __restrict__ x,
        const double* __restrict__ nrm2_d,
        const double* __restrict__ nrm_d,
        const double* __restrict__ simd,
        const unsigned char* __restrict__ adj,
        const float* __restrict__ e1_w, const float* __restrict__ e1_b,
        const float* __restrict__ e2_w, const float* __restrict__ e2_b,
        const float* __restrict__ gate_p,
        const float* __restrict__ q, const float* __restrict__ k,
        const float* __restrict__ v,
        unsigned short* __restrict__ ctxb) {
    int n = blockIdx.x;
    int tid = threadIdx.x;
    int w = tid >> 6, l = tid & 63;
    __shared__ unsigned short idxs[NN];
    __shared__ float w_sh[NHEAD][NN];
    __shared__ float ef2s[NN];
    __shared__ float ef3s[NN];
    __shared__ float qsh[NHEAD][HDIM];
    __shared__ int wtot[4];

    int c = 0; int loc[3];
    #pragma unroll
    for (int i = 0; i < 3; ++i) {
        int m = 3 * tid + i;
        if (adj[(size_t)n * NN + m]) loc[c++] = m;
    }
    int pc = c;
    #pragma unroll
    for (int off = 1; off < 64; off <<= 1) {
        int o = __shfl_up(pc, off);
        if (l >= off) pc += o;
    }
    if (l == 63) wtot[w] = pc;
    qsh[w][l] = q[((size_t)w * NN + n) * HDIM + l];
    __syncthreads();
    int base = 0;
    #pragma unroll
    for (int ww = 0; ww < 4; ++ww) if (ww < w) base += wtot[ww];
    int start = base + pc - c;
    for (int i = 0; i < c; ++i) idxs[start + i] = (unsigned short)loc[i];
    int cnt = wtot[0] + wtot[1] + wtot[2] + wtot[3];
    __syncthreads();

    float xa[4];
    #pragma unroll
    for (int i = 0; i < 4; ++i) xa[i] = x[(size_t)n * DD + l + 64 * i];

    for (int j = w; j < cnt; j += 4) {
        int m = idxs[j];
        float sab = 0.f, mab = 0.f;
        #pragma unroll
        for (int i = 0; i < 4; ++i) {
            float xb = x[(size_t)m * DD + l + 64 * i];
            float ad = fabsf(xa[i] - xb);
            sab += ad;
            mab = fmaxf(mab, ad);
        }
        #pragma unroll
        for (int off = 32; off > 0; off >>= 1) {
            sab += __shfl_xor(sab, off);
            mab = fmaxf(mab, __shfl_xor(mab, off));
        }
        if (l == 0) { ef2s[j] = sab * (1.f / 256.f); ef3s[j] = mab; }
    }
    __syncthreads();

    double nrm2n = nrm2_d[n];
    double nrmn  = nrm_d[n];
    float gate = gate_p[0];
    for (int j0 = 0; j0 < cnt; j0 += 64) {
        int j = j0 + (tid >> 2);
        int hh = tid & 3;
        if (j < cnt) {
            int m = idxs[j];
            double s_d   = simd[(size_t)n * NN + m];
            double nrm2m = nrm2_d[m];
            double dotd  = s_d * nrmn * nrm_d[m];
            double l2sq  = fmax(nrm2n + nrm2m - 2.0 * dotd, 0.0);
            float ef0 = (float)s_d;
            float ef1 = (float)(sqrt(l2sq) * (1.0 / 16.0));
            float ef2 = ef2s[j];
            float ef3 = ef3s[j];
            float bb = e2_b[hh];
            #pragma unroll
            for (int jj = 0; jj < 8; ++jj) {
                float hv = e1_b[jj] + ef0 * e1_w[0 * 8 + jj] + ef1 * e1_w[1 * 8 + jj]
                         + ef2 * e1_w[2 * 8 + jj] + ef3 * e1_w[3 * 8 + jj];
                bb += fmaxf(hv, 0.f) * e2_w[jj * 4 + hh];
            }
            w_sh[hh][j] = gate * bb;
        }
    }
    __syncthreads();

    int h = w;
    float lmax = -INFINITY;
    for (int j = l; j < cnt; j += 64) {
        int m = idxs[j];
        const float4* kr = (const float4*)(k + ((size_t)h * NN + m) * HDIM);
        float dotv = 0.f;
        #pragma unroll
        for (int d4 = 0; d4 < HDIM / 4; ++d4) {
            float4 kv = kr[d4];
            dotv += qsh[h][4 * d4 + 0] * kv.x + qsh[h][4 * d4 + 1] * kv.y
                  + qsh[h][4 * d4 + 2] * kv.z + qsh[h][4 * d4 + 3] * kv.w;
        }
        w_sh[h][j] = dotv * 0.125f + w_sh[h][j];
        lmax = fmaxf(lmax, w_sh[h][j]);
    }
    #pragma unroll
    for (int off = 32; off > 0; off >>= 1)
        lmax = fmaxf(lmax, __shfl_xor(lmax, off));

    float lsum = 0.f;
    for (int j = l; j < cnt; j += 64) {
        float e = expf(w_sh[h][j] - lmax);
        w_sh[h][j] = e;
        lsum += e;
    }
    #pragma unroll
    for (int off = 32; off > 0; off >>= 1) lsum += __shfl_xor(lsum, off);
    float inv = 1.f / lsum;
    __syncthreads();

    float acc = 0.f;
    #pragma unroll 4
    for (int j = 0; j < cnt; ++j)
        acc += w_sh[h][j] * v[((size_t)h * NN + idxs[j]) * HDIM + l];
    ctxb[(size_t)n * DD + h * HDIM + l] = f2bf(acc * inv);
}

// -------- LDS-free register MFMA GEMM: each wave owns one 16x16 tile
template<int KD, int MODE, bool CONCAT>
__global__ __launch_bounds__(256) void k_gemm_reg(const unsigned short* __restrict__ A,
                                                  const unsigned short* __restrict__ A2,
                                                  const unsigned short* __restrict__ Bt,
                                                  const float* __restrict__ bias,
                                                  const float* __restrict__ resid,
                                                  float* __restrict__ out,
                                                  unsigned short* __restrict__ outb,
                                                  int ncols) {
    int tid = threadIdx.x;
    int w = tid >> 6, lane = tid & 63;
    int m0 = blockIdx.y * 64 + w * 16;
    int n0 = blockIdx.x * 16;
    int fr = lane & 15, fg = lane >> 4;
    f32x4 acc = {0.f, 0.f, 0.f, 0.f};

    const unsigned short* brow = &Bt[(size_t)(n0 + fr) * KD];
    #pragma unroll
    for (int k0 = 0; k0 < KD; k0 += 32) {
        const unsigned short* Asrc = A; int koff = k0;
        if (CONCAT && k0 >= 256) { Asrc = A2; koff = k0 - 256; }
        int lda = CONCAT ? 256 : KD;
        short8 a = *(const short8*)&Asrc[(size_t)(m0 + fr) * lda + koff + fg * 8];
        short8 b = *(const short8*)&brow[k0 + fg * 8];
        acc = __builtin_amdgcn_mfma_f32_16x16x32_bf16(a, b, acc, 0, 0, 0);
    }

    int cidx = n0 + fr;
    float bb = bias[cidx];
    #pragma unroll
    for (int r = 0; r < 4; ++r) {
        int n = m0 + fg * 4 + r;
        float val = acc[r] + bb;
        if (MODE == 1) val += resid[(size_t)n * ncols + cidx];
        if (MODE == 3) outb[(size_t)n * ncols + cidx] = f2bf(val);
        else           out [(size_t)n * ncols + cidx] = val;
    }
}

// ------------------------------- LayerNorm + exact GELU -> bf16
__global__ __launch_bounds__(256) void k_ln_gelu(const float* __restrict__ y,
                                                 const float* __restrict__ g,
                                                 const float* __restrict__ b,
                                                 unsigned short* __restrict__ ybb) {
    int n = blockIdx.x;
    int tid = threadIdx.x;
    const float* row = y + (size_t)n * 512;
    __shared__ float red[256];
    float v0 = row[tid], v1 = row[tid + 256];

    red[tid] = v0 + v1; __syncthreads();
    for (int s = 128; s > 0; s >>= 1) {
        if (tid < s) red[tid] += red[tid + s];
        __syncthreads();
    }
    float mu = red[0] * (1.f / 512.f);
    __syncthreads();

    float d0 = v0 - mu, d1 = v1 - mu;
    red[tid] = d0 * d0 + d1 * d1; __syncthreads();
    for (int s = 128; s > 0; s >>= 1) {
        if (tid < s) red[tid] += red[tid + s];
        __syncthreads();
    }
    float var = red[0] * (1.f / 512.f);
    float rstd = 1.f / sqrtf(var + 1e-5f);

    float z0 = d0 * rstd * g[tid] + b[tid];
    float z1 = d1 * rstd * g[tid + 256] + b[tid + 256];
    float o0 = 0.5f * z0 * (1.f + erff(z0 * 0.70710678118654752f));
    float o1 = 0.5f * z1 * (1.f + erff(z1 * 0.70710678118654752f));
    ybb[(size_t)n * 512 + tid]       = f2bf(o0);
    ybb[(size_t)n * 512 + tid + 256] = f2bf(o1);
}

// --------------------------------------------------------------------- host
extern "C" void kernel_launch(void* const* d_in, const int* in_sizes, int n_in,
                              void* d_out, int out_size, void* d_ws, size_t ws_size,
                              hipStream_t stream) {
    const float* x       = (const float*)d_in[0];
    const float* Wqkv_w  = (const float*)d_in[1];
    const float* Wqkv_b  = (const float*)d_in[2];
    const float* out_w   = (const float*)d_in[3];
    const float* out_b   = (const float*)d_in[4];
    const float* ffn1_w  = (const float*)d_in[5];
    const float* ffn1_b  = (const float*)d_in[6];
    const float* ln_g    = (const float*)d_in[7];
    const float* ln_b    = (const float*)d_in[8];
    const float* ffn2_w  = (const float*)d_in[9];
    const float* ffn2_b  = (const float*)d_in[10];
    const float* e1_w    = (const float*)d_in[11];
    const float* e1_b    = (const float*)d_in[12];
    const float* e2_w    = (const float*)d_in[13];
    const float* e2_b    = (const float*)d_in[14];
    const float* gate    = (const float*)d_in[15];

    char* base = (char*)d_ws;
    double* simd   = (double*)base;            base += (size_t)NN * NN * 8;
    double* nrm2_d = (double*)base;            base += NN * 8;
    double* nrm_d  = (double*)base;            base += NN * 8;
    double* invn_d = (double*)base;            base += NN * 8;
    float* qb      = (float*)base;             base += (size_t)NN * DD * 4;
    float* kb      = (float*)base;             base += (size_t)NN * DD * 4;
    float* vb      = (float*)base;             base += (size_t)NN * DD * 4;
    float* yb      = (float*)base;             base += (size_t)NN * 512 * 4;
    unsigned char* adj = (unsigned char*)base;  base += (size_t)NN * NN;
    unsigned short* xbf  = (unsigned short*)base; base += (size_t)NN * DD * 2;
    unsigned short* ctxb = (unsigned short*)base; base += (size_t)NN * DD * 2;
    unsigned short* ybb  = (unsigned short*)base; base += (size_t)NN * 512 * 2;
    unsigned short* t_qkv = (unsigned short*)base; base += (size_t)768 * 256 * 2;
    unsigned short* t_f1  = (unsigned short*)base; base += (size_t)512 * 512 * 2;
    unsigned short* t_f2  = (unsigned short*)base; base += (size_t)256 * 512 * 2;
    unsigned short* t_g   = (unsigned short*)base; base += (size_t)512 * 512 * 2;
    unsigned short* t_outn = (unsigned short*)base; base += (size_t)256 * 256 * 2;
    float* bias_f  = (float*)base;             base += 512 * 4;

    k_prep_norms<<<832, 256, 0, stream>>>(Wqkv_w, out_w, ffn1_w, ffn2_w,
                                          t_qkv, t_f1, t_f2, t_g, t_outn,
                                          x, nrm2_d, nrm_d, invn_d, xbf,
                                          (unsigned int*)adj);

    k_simqkv<<<653, 512, 0, stream>>>(x, invn_d, simd, xbf, t_qkv, Wqkv_b,
                                      qb, kb, vb, t_f1, t_outn, t_g,
                                      out_b, ffn1_w, ffn1_b, bias_f);

    k_topk<<<192, 256, 0, stream>>>(simd, adj);

    k_edge_attn<<<NN, 256, 0, stream>>>(x, nrm2_d, nrm_d, simd, adj,
                                        e1_w, e1_b, e2_w, e2_b, gate,
                                        qb, kb, vb, ctxb);

    // y = x @ W1_top + ctx @ Wf + bias_f   (fp32 out)
    k_gemm_reg<512, 0, true><<<dim3(32, 12), 256, 0, stream>>>(
        xbf, ctxb, t_g, bias_f, nullptr, yb, nullptr, 512);

    k_ln_gelu<<<NN, 256, 0, stream>>>(yb, ln_g, ln_b, ybb);

    // out = x + GELU(LN(y)) @ ffn2_w + ffn2_b
    k_gemm_reg<512, 1, false><<<dim3(16, 12), 256, 0, stream>>>(
        ybb, nullptr, t_f2, ffn2_b, x, (float*)d_out, nullptr, DD);
}